// Round 2
// baseline (1383.526 us; speedup 1.0000x reference)
//
#include <hip/hip_runtime.h>
#include <math.h>

#define S_LEN 2048
#define BATCH 256
#define IN_DIM 64
#define HID 128

// Layout: 256 threads/block, 1 block = 1 batch element.
// tid -> (jg = tid & 31, ks = tid >> 5)
//   thread computes outputs j = 4*jg + r (r=0..3), k-segment ks:
//     Wh cols [16*ks, 16*ks+16), Wx cols [8*ks, 8*ks+8)
// K-split 8 partials reduced via LDS by threads 0..127 (thread j).

__launch_bounds__(256, 1)
__global__ void rnn_kernel(const float* __restrict__ x,
                           const float* __restrict__ Wx,
                           const float* __restrict__ bx,
                           const float* __restrict__ Wh,
                           const float* __restrict__ bh,
                           float* __restrict__ out) {
    __shared__ float h_lds[HID];
    __shared__ float partial[8][132];   // padded rows (132) to stagger banks

    const int tid = threadIdx.x;
    const int b   = blockIdx.x;
    const int jg  = tid & 31;
    const int ks  = tid >> 5;
    const int j0  = jg * 4;

    // ---- load weight slices into registers (once; L2-shared across blocks)
    float wh[4][16];
    float wx[4][8];
#pragma unroll
    for (int r = 0; r < 4; ++r) {
        const float* whrow = Wh + (j0 + r) * HID + ks * 16;
#pragma unroll
        for (int i4 = 0; i4 < 4; ++i4) {
            float4 v = *reinterpret_cast<const float4*>(whrow + i4 * 4);
            wh[r][i4 * 4 + 0] = v.x;
            wh[r][i4 * 4 + 1] = v.y;
            wh[r][i4 * 4 + 2] = v.z;
            wh[r][i4 * 4 + 3] = v.w;
        }
        const float* wxrow = Wx + (j0 + r) * IN_DIM + ks * 8;
#pragma unroll
        for (int i4 = 0; i4 < 2; ++i4) {
            float4 v = *reinterpret_cast<const float4*>(wxrow + i4 * 4);
            wx[r][i4 * 4 + 0] = v.x;
            wx[r][i4 * 4 + 1] = v.y;
            wx[r][i4 * 4 + 2] = v.z;
            wx[r][i4 * 4 + 3] = v.w;
        }
    }

    // bias for the reduce phase (thread j = tid < 128)
    float bias = 0.0f;
    if (tid < HID) bias = bh[tid] + bx[tid];

    if (tid < HID) h_lds[tid] = 0.0f;

    // prefetch x[0][b][8ks .. 8ks+8)
    const float* xb = x + (size_t)b * IN_DIM;
    float4 xv0 = *reinterpret_cast<const float4*>(xb + ks * 8);
    float4 xv1 = *reinterpret_cast<const float4*>(xb + ks * 8 + 4);

    __syncthreads();

    float* outb = out + (size_t)b * HID;

    for (int t = 0; t < S_LEN; ++t) {
        float acc0 = 0.f, acc1 = 0.f, acc2 = 0.f, acc3 = 0.f;

        // x contribution first (registers already resident — covers LDS latency)
        float xr[8] = {xv0.x, xv0.y, xv0.z, xv0.w, xv1.x, xv1.y, xv1.z, xv1.w};
#pragma unroll
        for (int i = 0; i < 8; ++i) {
            acc0 += wx[0][i] * xr[i];
            acc1 += wx[1][i] * xr[i];
            acc2 += wx[2][i] * xr[i];
            acc3 += wx[3][i] * xr[i];
        }

        // prefetch next step's x while h-FMAs run
        if (t + 1 < S_LEN) {
            const float* xn = xb + (size_t)(t + 1) * (BATCH * IN_DIM) + ks * 8;
            xv0 = *reinterpret_cast<const float4*>(xn);
            xv1 = *reinterpret_cast<const float4*>(xn + 4);
        }

        // h contribution: broadcast reads from LDS (half-wave-uniform addresses)
#pragma unroll
        for (int i4 = 0; i4 < 4; ++i4) {
            float4 hv = *reinterpret_cast<const float4*>(&h_lds[ks * 16 + i4 * 4]);
            float hvv[4] = {hv.x, hv.y, hv.z, hv.w};
#pragma unroll
            for (int i = 0; i < 4; ++i) {
                const float h_ = hvv[i];
                acc0 += wh[0][i4 * 4 + i] * h_;
                acc1 += wh[1][i4 * 4 + i] * h_;
                acc2 += wh[2][i4 * 4 + i] * h_;
                acc3 += wh[3][i4 * 4 + i] * h_;
            }
        }

        // contiguous b128 partial write
        float4 p = make_float4(acc0, acc1, acc2, acc3);
        *reinterpret_cast<float4*>(&partial[ks][j0]) = p;

        __syncthreads();

        // reduce + activation + store (threads 0..127, thread == output dim j)
        if (tid < HID) {
            float s = bias;
#pragma unroll
            for (int k = 0; k < 8; ++k) s += partial[k][tid];
            const float hn = tanhf(s);
            h_lds[tid] = hn;
            outb[(size_t)t * (BATCH * HID) + tid] = hn;
        }

        __syncthreads();
    }

    // h_last (appended after h_seq in the flat output)
    if (tid < HID) {
        out[(size_t)S_LEN * BATCH * HID + (size_t)b * HID + tid] = h_lds[tid];
    }
}

extern "C" void kernel_launch(void* const* d_in, const int* in_sizes, int n_in,
                              void* d_out, int out_size, void* d_ws, size_t ws_size,
                              hipStream_t stream) {
    const float* x  = (const float*)d_in[0];
    const float* Wx = (const float*)d_in[1];
    const float* bx = (const float*)d_in[2];
    const float* Wh = (const float*)d_in[3];
    const float* bh = (const float*)d_in[4];
    float* out = (float*)d_out;

    rnn_kernel<<<dim3(BATCH), dim3(256), 0, stream>>>(x, Wx, bx, Wh, bh, out);
}